// Round 4
// baseline (5332.499 us; speedup 1.0000x reference)
//
#include <hip/hip_runtime.h>
#include <hip/hip_bf16.h>

// Neural ODE Euler rollout, persistent weight-stationary model-parallel kernel.
// B=256, T=128, X=256, H=1024, L=3.
// 4 groups x 64 blocks; group g owns batch rows [64g,64g+64).
// Block j owns 16 H-cols; weights resident in LDS; activations exchanged via
// coherent (sc0 sc1) relaxed agent atomics; NO fences in the loop (R3 lesson:
// agent fences = buffer_wbl2/inv storms, 37us/phase).
//
// Round-4 changes:
//  (a) atomic-free barrier: per-block epoch slot + wave-parallel 64-lane poll
//      with __all ballot (R3's single-line atomic_fetch_add serialized 64 RMWs).
//  (b) 5->4 phases/step: u = y@Win + bin carried in fp32 regs;
//      u += dt*(z@Wcomp + bout@Win), Wcomp = Wout@Win precomputed per-block
//      into LDS by MFMA. a0 = tanh(u) produced locally (phase A eliminated).
//  (c) all 32 A-fragments prefetched to VGPRs before the MFMA chain (one
//      latency exposure, not four).

typedef __attribute__((ext_vector_type(8))) short short8;
typedef __attribute__((ext_vector_type(4))) float f32x4;

#define AT_LD(p) __hip_atomic_load((p), __ATOMIC_RELAXED, __HIP_MEMORY_SCOPE_AGENT)
#define AT_ST(p, v) \
  __hip_atomic_store((p), (v), __ATOMIC_RELAXED, __HIP_MEMORY_SCOPE_AGENT)

__device__ inline unsigned short f2bf(float f) {
  unsigned u = __builtin_bit_cast(unsigned, f);
  unsigned r = u + 0x7FFFu + ((u >> 16) & 1u);
  return (unsigned short)(r >> 16);
}

// 16B coherent fragment load as 2x8B relaxed agent atomics (sc0 sc1 bypass).
__device__ inline short8 ld_frag(const unsigned short* p) {
  union { unsigned long long q[2]; short8 v; } u;
  unsigned long long* q = (unsigned long long*)p;
  u.q[0] = AT_LD(q);
  u.q[1] = AT_LD(q + 1);
  return u.v;
}

__global__ __launch_bounds__(256, 1) void node_persistent(
    const float* __restrict__ x, const float* __restrict__ ts,
    const float* __restrict__ Win, const float* __restrict__ bin,
    const float* __restrict__ Wh, const float* __restrict__ bh,
    const float* __restrict__ Wout, const float* __restrict__ bout,
    float* __restrict__ out,
    unsigned* __restrict__ cnt,
    unsigned short* __restrict__ a0,
    unsigned short* __restrict__ a1) {
  // LDS: fragment-major slices. Element (k,c) -> ((k>>3)*16 + c)*8 + (k&7)
  alignas(16) __shared__ unsigned short sWh[3][16384];   // 96 KB
  alignas(16) __shared__ unsigned short sWcomp[16384];   // 32 KB (Wout@Win slice)
  alignas(16) __shared__ unsigned short sWin[4096];      // 8 KB (prologue only)
  __shared__ float sBin[16], sBh[3][16], sBout[16], sBWc[16];
  __shared__ float sDt[128];

  const int bid = blockIdx.x;
  const int g = (bid & 7) >> 1;                 // group 0..3 (XCD pair {2g,2g+1})
  const int j = ((bid >> 3) << 1) | (bid & 1);  // n-slice 0..63
  const int tid = threadIdx.x;
  const int w = tid >> 6;       // wave 0..3 -> 16-row M tile
  const int l = tid & 63;       // lane
  const int lr = l & 15;        // A row / B col / D col
  const int lk = l >> 4;        // k-chunk; D rows = 4*lk + r
  const int rowbase = g * 64 + w * 16;
  unsigned* slots = cnt + g * 64;  // 64 epoch dwords per group (256B)

  // ---- stage sWin, sWh, biases ----
  for (int idx = tid; idx < 256 * 16; idx += 256) {
    int k = idx >> 4, c = idx & 15;
    sWin[((k >> 3) * 16 + c) * 8 + (k & 7)] = f2bf(Win[k * 1024 + j * 16 + c]);
  }
  for (int l3 = 0; l3 < 3; ++l3)
    for (int idx = tid; idx < 1024 * 16; idx += 256) {
      int k = idx >> 4, c = idx & 15;
      sWh[l3][((k >> 3) * 16 + c) * 8 + (k & 7)] =
          f2bf(Wh[(l3 * 1024 + k) * 1024 + j * 16 + c]);
    }
  if (tid < 16) {
    sBin[tid] = bin[j * 16 + tid];
    sBh[0][tid] = bh[j * 16 + tid];
    sBh[1][tid] = bh[1024 + j * 16 + tid];
    sBh[2][tid] = bh[2048 + j * 16 + tid];
    if (j < 16) sBout[tid] = bout[j * 16 + tid];
    float s = 0.f;  // bWc = bout @ Win (own 16 cols)
    for (int xx = 0; xx < 256; ++xx) s += bout[xx] * Win[xx * 1024 + j * 16 + tid];
    sBWc[tid] = s;
  }
  if (tid < 127) sDt[tid] = ts[tid + 1] - ts[tid];
  __syncthreads();

  // ---- one-time: sWcomp = (Wout @ Win)[:, own 16 cols] via MFMA ----
  for (int i = 0; i < 16; ++i) {
    int mt = w * 16 + i;  // 64 m-tiles of 16 rows over the 1024 k-dim
    f32x4 acc = {0.f, 0.f, 0.f, 0.f};
    const float* abase = Wout + (mt * 16 + lr) * 256 + lk * 8;
#pragma unroll
    for (int kk = 0; kk < 8; ++kk) {
      float4 f0 = *(const float4*)(abase + kk * 32);
      float4 f1 = *(const float4*)(abase + kk * 32 + 4);
      short8 a;
      a[0] = (short)f2bf(f0.x); a[1] = (short)f2bf(f0.y);
      a[2] = (short)f2bf(f0.z); a[3] = (short)f2bf(f0.w);
      a[4] = (short)f2bf(f1.x); a[5] = (short)f2bf(f1.y);
      a[6] = (short)f2bf(f1.z); a[7] = (short)f2bf(f1.w);
      short8 b = *(const short8*)(sWin + lk * 128 + lr * 8 + kk * 512);
      acc = __builtin_amdgcn_mfma_f32_16x16x32_bf16(a, b, acc, 0, 0, 0);
    }
#pragma unroll
    for (int r4 = 0; r4 < 4; ++r4) {
      int k = mt * 16 + lk * 4 + r4;
      sWcomp[((k >> 3) * 16 + lr) * 8 + (k & 7)] = f2bf(acc[r4]);
    }
  }

  // ---- u0 = x @ Win + bin (fp32 regs); a0 = tanh(u0) ----
  f32x4 u;
  {
    f32x4 acc = {0.f, 0.f, 0.f, 0.f};
    const float* xbase = x + (rowbase + lr) * 256 + lk * 8;
#pragma unroll
    for (int kk = 0; kk < 8; ++kk) {
      float4 f0 = *(const float4*)(xbase + kk * 32);
      float4 f1 = *(const float4*)(xbase + kk * 32 + 4);
      short8 a;
      a[0] = (short)f2bf(f0.x); a[1] = (short)f2bf(f0.y);
      a[2] = (short)f2bf(f0.z); a[3] = (short)f2bf(f0.w);
      a[4] = (short)f2bf(f1.x); a[5] = (short)f2bf(f1.y);
      a[6] = (short)f2bf(f1.z); a[7] = (short)f2bf(f1.w);
      short8 b = *(const short8*)(sWin + lk * 128 + lr * 8 + kk * 512);
      acc = __builtin_amdgcn_mfma_f32_16x16x32_bf16(a, b, acc, 0, 0, 0);
    }
    const int colH = j * 16 + lr;
#pragma unroll
    for (int r4 = 0; r4 < 4; ++r4) {
      u[r4] = acc[r4] + sBin[lr];
      AT_ST(&a0[(rowbase + lk * 4 + r4) * 1024 + colH], f2bf(tanhf(u[r4])));
    }
  }

  // ---- j<16: yreg, out[:,0,:], Wout B-fragments into VGPRs ----
  f32x4 yreg = {0.f, 0.f, 0.f, 0.f};
  short8 wfrag[32];
  if (j < 16) {
    for (int idx = tid; idx < 64 * 16; idx += 256) {
      int r = idx >> 4, c = idx & 15;
      int row = g * 64 + r, col = j * 16 + c;
      out[(row * 128) * 256 + col] = x[row * 256 + col];  // pred[:,0,:] = x
    }
#pragma unroll
    for (int r4 = 0; r4 < 4; ++r4)
      yreg[r4] = x[(rowbase + lk * 4 + r4) * 256 + j * 16 + lr];
#pragma unroll
    for (int kk = 0; kk < 32; ++kk) {
      short8 wv;
#pragma unroll
      for (int d = 0; d < 8; ++d)
        wv[d] = (short)f2bf(Wout[(lk * 8 + kk * 32 + d) * 256 + j * 16 + lr]);
      wfrag[kk] = wv;
    }
  }

  // ---- atomic-free group barrier: own-slot store + 64-lane poll ----
  unsigned bn = 0;
  auto BAR = [&]() {
    ++bn;
    __syncthreads();  // s_waitcnt vmcnt(0): coherent stores are at IF$
    if (tid < 64) {
      if (tid == 0) AT_ST(&slots[j], bn);
      for (;;) {
        unsigned v = AT_LD(&slots[tid]);
        if (__all((int)(v >= bn || tid == (unsigned)j))) break;
        __builtin_amdgcn_s_sleep(1);
      }
    }
    __syncthreads();
  };

  BAR();  // a0 + everything staged, visible group-wide

  const int colH = j * 16 + lr;
  for (int t = 0; t < 127; ++t) {
    // ---- Phases B,C,D: h = tanh(h_prev)@Wh[l3] + bh[l3] ----
    for (int l3 = 0; l3 < 3; ++l3) {
      const unsigned short* src = (l3 == 1) ? a1 : a0;
      unsigned short* dst = (l3 == 1) ? a0 : a1;
      const unsigned short* arow = src + (rowbase + lr) * 1024 + lk * 8;
      short8 af[32];
#pragma unroll
      for (int kk = 0; kk < 32; ++kk) af[kk] = ld_frag(arow + kk * 32);
      f32x4 acc = {0.f, 0.f, 0.f, 0.f};
#pragma unroll
      for (int kk = 0; kk < 32; ++kk) {
        short8 b = *(const short8*)(sWh[l3] + lk * 128 + lr * 8 + kk * 512);
        acc = __builtin_amdgcn_mfma_f32_16x16x32_bf16(af[kk], b, acc, 0, 0, 0);
      }
      float bias = sBh[l3][lr];
#pragma unroll
      for (int r4 = 0; r4 < 4; ++r4)
        AT_ST(&dst[(rowbase + lk * 4 + r4) * 1024 + colH],
              f2bf(tanhf(acc[r4] + bias)));
      BAR();
    }
    // ---- Phase E': z@Wcomp updates u; j<16 also z@Wout -> y, out ----
    {
      float dt = sDt[t];
      const unsigned short* arow = a1 + (rowbase + lr) * 1024 + lk * 8;
      short8 af[32];
#pragma unroll
      for (int kk = 0; kk < 32; ++kk) af[kk] = ld_frag(arow + kk * 32);
      f32x4 accC = {0.f, 0.f, 0.f, 0.f};
#pragma unroll
      for (int kk = 0; kk < 32; ++kk) {
        short8 b = *(const short8*)(sWcomp + lk * 128 + lr * 8 + kk * 512);
        accC = __builtin_amdgcn_mfma_f32_16x16x32_bf16(af[kk], b, accC, 0, 0, 0);
      }
#pragma unroll
      for (int r4 = 0; r4 < 4; ++r4) {
        u[r4] += dt * (accC[r4] + sBWc[lr]);
        AT_ST(&a0[(rowbase + lk * 4 + r4) * 1024 + colH], f2bf(tanhf(u[r4])));
      }
      if (j < 16) {
        f32x4 accO = {0.f, 0.f, 0.f, 0.f};
#pragma unroll
        for (int kk = 0; kk < 32; ++kk)
          accO = __builtin_amdgcn_mfma_f32_16x16x32_bf16(af[kk], wfrag[kk],
                                                         accO, 0, 0, 0);
#pragma unroll
        for (int r4 = 0; r4 < 4; ++r4) {
          float yv = yreg[r4] + dt * (accO[r4] + sBout[lr]);
          yreg[r4] = yv;
          int row = rowbase + lk * 4 + r4;
          out[(row * 128 + t + 1) * 256 + j * 16 + lr] = yv;
        }
      }
      BAR();
    }
  }
}

extern "C" void kernel_launch(void* const* d_in, const int* in_sizes, int n_in,
                              void* d_out, int out_size, void* d_ws, size_t ws_size,
                              hipStream_t stream) {
  (void)in_sizes; (void)n_in; (void)out_size; (void)ws_size;
  const float* x    = (const float*)d_in[0];
  const float* ts   = (const float*)d_in[1];
  const float* Win  = (const float*)d_in[2];
  const float* bin  = (const float*)d_in[3];
  const float* Wh   = (const float*)d_in[4];
  const float* bh   = (const float*)d_in[5];
  const float* Wout = (const float*)d_in[6];
  const float* bout = (const float*)d_in[7];
  float* out = (float*)d_out;

  char* ws = (char*)d_ws;
  unsigned* cnt = (unsigned*)ws;                               // 4 KB epoch slots
  unsigned short* a0 = (unsigned short*)(ws + 4096);           // 512 KB
  unsigned short* a1 = (unsigned short*)(ws + 4096 + 524288);  // 512 KB

  hipMemsetAsync(ws, 0, 4096, stream);  // zero epoch slots each call

  // Persistent spin-barrier kernel: co-residency of all 256 blocks required.
  void* args[] = {(void*)&x,    (void*)&ts,  (void*)&Win,  (void*)&bin,
                  (void*)&Wh,   (void*)&bh,  (void*)&Wout, (void*)&bout,
                  (void*)&out,  (void*)&cnt, (void*)&a0,   (void*)&a1};
  hipError_t e = hipLaunchCooperativeKernel((const void*)node_persistent,
                                            dim3(256), dim3(256), args, 0, stream);
  if (e != hipSuccess) {
    hipLaunchKernelGGL(node_persistent, dim3(256), dim3(256), 0, stream,
                       x, ts, Win, bin, Wh, bh, Wout, bout, out, cnt, a0, a1);
  }
}

// Round 5
// 3081.013 us; speedup vs baseline: 1.7308x; 1.7308x over previous
//
#include <hip/hip_runtime.h>
#include <hip/hip_bf16.h>

// Neural ODE Euler rollout, persistent weight-stationary model-parallel kernel.
// B=256, T=128, X=256, H=1024, L=3.
// 4 groups x 64 blocks; group g owns batch rows [64g,64g+64).
// Block j owns 16 H-cols; weights resident in LDS; activations exchanged via
// coherent (sc0 sc1) bypass ops; NO fences in the loop (R2 lesson: agent
// fences = buffer_wbl2/inv storms). Atomic-free epoch barrier (R4).
//
// Round-5 change (R4 post-mortem: time tracks bypass-read volume; row-major
// panel made each wave-load fragment into 16 small fabric transactions):
//  FRAGMENT-MAJOR activation panels: (r,c) -> (r>>4)*16384 + (c>>5)*512
//  + ((c>>3)&3)*128 + (r&15)*8 + (c&7). Consumer wave reads contiguous 1KB
//  per instruction via inline-asm global_load_dwordx4 sc0 sc1 (16B/lane),
//  32 loads batched under one vmcnt(0) + sched_barrier(0)  [rule #18].

typedef __attribute__((ext_vector_type(8))) short short8;
typedef __attribute__((ext_vector_type(4))) float f32x4;

#define AT_LD(p) __hip_atomic_load((p), __ATOMIC_RELAXED, __HIP_MEMORY_SCOPE_AGENT)
#define AT_ST(p, v) \
  __hip_atomic_store((p), (v), __ATOMIC_RELAXED, __HIP_MEMORY_SCOPE_AGENT)

// Coherent 16B bypass load (L1/L2-bypassing, served at IF$ coherence point).
#define GLD_BYPASS(dst, ptr) \
  asm volatile("global_load_dwordx4 %0, %1, off sc0 sc1" \
               : "=v"(dst) : "v"(ptr) : "memory")
#define VM_WAIT0()                                   \
  do {                                               \
    asm volatile("s_waitcnt vmcnt(0)" ::: "memory"); \
    __builtin_amdgcn_sched_barrier(0);               \
  } while (0)

__device__ inline unsigned short f2bf(float f) {
  unsigned u = __builtin_bit_cast(unsigned, f);
  unsigned r = u + 0x7FFFu + ((u >> 16) & 1u);
  return (unsigned short)(r >> 16);
}

__global__ __launch_bounds__(256, 1) void node_persistent(
    const float* __restrict__ x, const float* __restrict__ ts,
    const float* __restrict__ Win, const float* __restrict__ bin,
    const float* __restrict__ Wh, const float* __restrict__ bh,
    const float* __restrict__ Wout, const float* __restrict__ bout,
    float* __restrict__ out,
    unsigned* __restrict__ cnt,
    unsigned short* __restrict__ a0,
    unsigned short* __restrict__ a1) {
  // LDS: fragment-major slices. Element (k,c) -> ((k>>3)*16 + c)*8 + (k&7)
  alignas(16) __shared__ unsigned short sWh[3][16384];   // 96 KB
  alignas(16) __shared__ unsigned short sWcomp[16384];   // 32 KB (Wout@Win slice)
  alignas(16) __shared__ unsigned short sWin[4096];      // 8 KB (prologue only)
  __shared__ float sBin[16], sBh[3][16], sBout[16], sBWc[16];
  __shared__ float sDt[128];

  const int bid = blockIdx.x;
  const int g = (bid & 7) >> 1;                 // group 0..3 (XCD pair {2g,2g+1})
  const int j = ((bid >> 3) << 1) | (bid & 1);  // n-slice 0..63
  const int tid = threadIdx.x;
  const int w = tid >> 6;       // wave 0..3 -> 16-row M tile
  const int l = tid & 63;       // lane
  const int lr = l & 15;        // A row / B col / D col
  const int lk = l >> 4;        // k-chunk; D rows = 4*lk + r
  const int rowbase = g * 64 + w * 16;
  unsigned* slots = cnt + g * 64;  // 64 epoch dwords per group (256B)

  // ---- stage sWin, sWh, biases ----
  for (int idx = tid; idx < 256 * 16; idx += 256) {
    int k = idx >> 4, c = idx & 15;
    sWin[((k >> 3) * 16 + c) * 8 + (k & 7)] = f2bf(Win[k * 1024 + j * 16 + c]);
  }
  for (int l3 = 0; l3 < 3; ++l3)
    for (int idx = tid; idx < 1024 * 16; idx += 256) {
      int k = idx >> 4, c = idx & 15;
      sWh[l3][((k >> 3) * 16 + c) * 8 + (k & 7)] =
          f2bf(Wh[(l3 * 1024 + k) * 1024 + j * 16 + c]);
    }
  if (tid < 16) {
    sBin[tid] = bin[j * 16 + tid];
    sBh[0][tid] = bh[j * 16 + tid];
    sBh[1][tid] = bh[1024 + j * 16 + tid];
    sBh[2][tid] = bh[2048 + j * 16 + tid];
    if (j < 16) sBout[tid] = bout[j * 16 + tid];
    float s = 0.f;  // bWc = bout @ Win (own 16 cols)
    for (int xx = 0; xx < 256; ++xx) s += bout[xx] * Win[xx * 1024 + j * 16 + tid];
    sBWc[tid] = s;
  }
  if (tid < 127) sDt[tid] = ts[tid + 1] - ts[tid];
  __syncthreads();

  // ---- one-time: sWcomp = (Wout @ Win)[:, own 16 cols] via MFMA ----
  for (int i = 0; i < 16; ++i) {
    int mt = w * 16 + i;  // 64 m-tiles of 16 rows over the 1024 k-dim
    f32x4 acc = {0.f, 0.f, 0.f, 0.f};
    const float* abase = Wout + (mt * 16 + lr) * 256 + lk * 8;
#pragma unroll
    for (int kk = 0; kk < 8; ++kk) {
      float4 f0 = *(const float4*)(abase + kk * 32);
      float4 f1 = *(const float4*)(abase + kk * 32 + 4);
      short8 a;
      a[0] = (short)f2bf(f0.x); a[1] = (short)f2bf(f0.y);
      a[2] = (short)f2bf(f0.z); a[3] = (short)f2bf(f0.w);
      a[4] = (short)f2bf(f1.x); a[5] = (short)f2bf(f1.y);
      a[6] = (short)f2bf(f1.z); a[7] = (short)f2bf(f1.w);
      short8 b = *(const short8*)(sWin + lk * 128 + lr * 8 + kk * 512);
      acc = __builtin_amdgcn_mfma_f32_16x16x32_bf16(a, b, acc, 0, 0, 0);
    }
#pragma unroll
    for (int r4 = 0; r4 < 4; ++r4) {
      int k = mt * 16 + lk * 4 + r4;
      sWcomp[((k >> 3) * 16 + lr) * 8 + (k & 7)] = f2bf(acc[r4]);
    }
  }

  // Fragment-major panel addressing: base offset for this thread's produced
  // column c (rows vary by lk*4+r4):
  unsigned short* a0g = a0 + (g << 16);
  unsigned short* a1g = a1 + (g << 16);
  const int colH = j * 16 + lr;
  const int pstore = (w << 14) + ((colH >> 5) << 9) + (((colH >> 3) & 3) << 7) +
                     (colH & 7);

  // ---- u0 = x @ Win + bin (fp32 regs); a0 = tanh(u0) ----
  f32x4 u;
  {
    f32x4 acc = {0.f, 0.f, 0.f, 0.f};
    const float* xbase = x + (rowbase + lr) * 256 + lk * 8;
#pragma unroll
    for (int kk = 0; kk < 8; ++kk) {
      float4 f0 = *(const float4*)(xbase + kk * 32);
      float4 f1 = *(const float4*)(xbase + kk * 32 + 4);
      short8 a;
      a[0] = (short)f2bf(f0.x); a[1] = (short)f2bf(f0.y);
      a[2] = (short)f2bf(f0.z); a[3] = (short)f2bf(f0.w);
      a[4] = (short)f2bf(f1.x); a[5] = (short)f2bf(f1.y);
      a[6] = (short)f2bf(f1.z); a[7] = (short)f2bf(f1.w);
      short8 b = *(const short8*)(sWin + lk * 128 + lr * 8 + kk * 512);
      acc = __builtin_amdgcn_mfma_f32_16x16x32_bf16(a, b, acc, 0, 0, 0);
    }
#pragma unroll
    for (int r4 = 0; r4 < 4; ++r4) {
      u[r4] = acc[r4] + sBin[lr];
      AT_ST(&a0g[pstore + ((lk * 4 + r4) << 3)], f2bf(tanhf(u[r4])));
    }
  }

  // ---- j<16: yreg, out[:,0,:], Wout B-fragments into VGPRs ----
  f32x4 yreg = {0.f, 0.f, 0.f, 0.f};
  short8 wfrag[32];
  if (j < 16) {
    for (int idx = tid; idx < 64 * 16; idx += 256) {
      int r = idx >> 4, c = idx & 15;
      int row = g * 64 + r, col = j * 16 + c;
      out[(row * 128) * 256 + col] = x[row * 256 + col];  // pred[:,0,:] = x
    }
#pragma unroll
    for (int r4 = 0; r4 < 4; ++r4)
      yreg[r4] = x[(rowbase + lk * 4 + r4) * 256 + j * 16 + lr];
#pragma unroll
    for (int kk = 0; kk < 32; ++kk) {
      short8 wv;
#pragma unroll
      for (int d = 0; d < 8; ++d)
        wv[d] = (short)f2bf(Wout[(lk * 8 + kk * 32 + d) * 256 + j * 16 + lr]);
      wfrag[kk] = wv;
    }
  }

  // ---- atomic-free group barrier: own-slot store + 64-lane poll ----
  unsigned bn = 0;
  auto BAR = [&]() {
    ++bn;
    __syncthreads();  // s_waitcnt vmcnt(0): coherent stores are at IF$
    if (tid < 64) {
      if (tid == 0) AT_ST(&slots[j], bn);
      for (;;) {
        unsigned v = AT_LD(&slots[tid]);
        if (__all((int)(v >= bn || tid == (unsigned)j))) break;
        __builtin_amdgcn_s_sleep(1);
      }
    }
    __syncthreads();
  };

  BAR();  // a0 + everything staged, visible group-wide

  for (int t = 0; t < 127; ++t) {
    // ---- Phases B,C,D: h = tanh(h_prev)@Wh[l3] + bh[l3] ----
    for (int l3 = 0; l3 < 3; ++l3) {
      const unsigned short* src = (l3 == 1) ? a1g : a0g;
      unsigned short* dst = (l3 == 1) ? a0g : a1g;
      const unsigned short* pb = src + (w << 14) + (l << 3);
      short8 af[32];
#pragma unroll
      for (int kk = 0; kk < 32; ++kk) GLD_BYPASS(af[kk], pb + (kk << 9));
      VM_WAIT0();
      f32x4 ac0 = {0.f, 0.f, 0.f, 0.f}, ac1 = {0.f, 0.f, 0.f, 0.f};
#pragma unroll
      for (int kk = 0; kk < 32; kk += 2) {
        short8 b0 = *(const short8*)(sWh[l3] + lk * 128 + lr * 8 + kk * 512);
        short8 b1 = *(const short8*)(sWh[l3] + lk * 128 + lr * 8 + (kk + 1) * 512);
        ac0 = __builtin_amdgcn_mfma_f32_16x16x32_bf16(af[kk], b0, ac0, 0, 0, 0);
        ac1 = __builtin_amdgcn_mfma_f32_16x16x32_bf16(af[kk + 1], b1, ac1, 0, 0, 0);
      }
      f32x4 acc = ac0 + ac1;
      float bias = sBh[l3][lr];
#pragma unroll
      for (int r4 = 0; r4 < 4; ++r4)
        AT_ST(&dst[pstore + ((lk * 4 + r4) << 3)], f2bf(tanhf(acc[r4] + bias)));
      BAR();
    }
    // ---- Phase E': z@Wcomp updates u; j<16 also z@Wout -> y, out ----
    {
      float dt = sDt[t];
      const unsigned short* pb = a1g + (w << 14) + (l << 3);
      short8 af[32];
#pragma unroll
      for (int kk = 0; kk < 32; ++kk) GLD_BYPASS(af[kk], pb + (kk << 9));
      VM_WAIT0();
      f32x4 ac0 = {0.f, 0.f, 0.f, 0.f}, ac1 = {0.f, 0.f, 0.f, 0.f};
#pragma unroll
      for (int kk = 0; kk < 32; kk += 2) {
        short8 b0 = *(const short8*)(sWcomp + lk * 128 + lr * 8 + kk * 512);
        short8 b1 = *(const short8*)(sWcomp + lk * 128 + lr * 8 + (kk + 1) * 512);
        ac0 = __builtin_amdgcn_mfma_f32_16x16x32_bf16(af[kk], b0, ac0, 0, 0, 0);
        ac1 = __builtin_amdgcn_mfma_f32_16x16x32_bf16(af[kk + 1], b1, ac1, 0, 0, 0);
      }
      f32x4 accC = ac0 + ac1;
#pragma unroll
      for (int r4 = 0; r4 < 4; ++r4) {
        u[r4] += dt * (accC[r4] + sBWc[lr]);
        AT_ST(&a0g[pstore + ((lk * 4 + r4) << 3)], f2bf(tanhf(u[r4])));
      }
      if (j < 16) {
        f32x4 accO = {0.f, 0.f, 0.f, 0.f};
#pragma unroll
        for (int kk = 0; kk < 32; ++kk)
          accO = __builtin_amdgcn_mfma_f32_16x16x32_bf16(af[kk], wfrag[kk],
                                                         accO, 0, 0, 0);
#pragma unroll
        for (int r4 = 0; r4 < 4; ++r4) {
          float yv = yreg[r4] + dt * (accO[r4] + sBout[lr]);
          yreg[r4] = yv;
          int row = rowbase + lk * 4 + r4;
          out[(row * 128 + t + 1) * 256 + j * 16 + lr] = yv;
        }
      }
      BAR();
    }
  }
}

extern "C" void kernel_launch(void* const* d_in, const int* in_sizes, int n_in,
                              void* d_out, int out_size, void* d_ws, size_t ws_size,
                              hipStream_t stream) {
  (void)in_sizes; (void)n_in; (void)out_size; (void)ws_size;
  const float* x    = (const float*)d_in[0];
  const float* ts   = (const float*)d_in[1];
  const float* Win  = (const float*)d_in[2];
  const float* bin  = (const float*)d_in[3];
  const float* Wh   = (const float*)d_in[4];
  const float* bh   = (const float*)d_in[5];
  const float* Wout = (const float*)d_in[6];
  const float* bout = (const float*)d_in[7];
  float* out = (float*)d_out;

  char* ws = (char*)d_ws;
  unsigned* cnt = (unsigned*)ws;                               // 4 KB epoch slots
  unsigned short* a0 = (unsigned short*)(ws + 4096);           // 512 KB
  unsigned short* a1 = (unsigned short*)(ws + 4096 + 524288);  // 512 KB

  hipMemsetAsync(ws, 0, 4096, stream);  // zero epoch slots each call

  // Persistent spin-barrier kernel: co-residency of all 256 blocks required.
  void* args[] = {(void*)&x,    (void*)&ts,  (void*)&Win,  (void*)&bin,
                  (void*)&Wh,   (void*)&bh,  (void*)&Wout, (void*)&bout,
                  (void*)&out,  (void*)&cnt, (void*)&a0,   (void*)&a1};
  hipError_t e = hipLaunchCooperativeKernel((const void*)node_persistent,
                                            dim3(256), dim3(256), args, 0, stream);
  if (e != hipSuccess) {
    hipLaunchKernelGGL(node_persistent, dim3(256), dim3(256), 0, stream,
                       x, ts, Win, bin, Wh, bh, Wout, bout, out, cnt, a0, a1);
  }
}